// Round 7
// baseline (273.193 us; speedup 1.0000x reference)
//
#include <hip/hip_runtime.h>
#include <hip/hip_bf16.h>
#include <cstdint>
#include <cstddef>

// Problem constants
#define S_LEN 2048
#define DMODEL 2048
#define NHEADS 8
#define DHEAD 128
#define INNER_DIM 1024
#define BATCH 2

typedef __bf16 bf16;
typedef __bf16 bf16x8 __attribute__((ext_vector_type(8)));
typedef __bf16 bf16x4 __attribute__((ext_vector_type(4)));
typedef float f32x4 __attribute__((ext_vector_type(4)));

#define VMCNT(n) asm volatile("s_waitcnt vmcnt(" #n ")" ::: "memory")
#define BAR()                                \
  do {                                       \
    asm volatile("" ::: "memory");           \
    __builtin_amdgcn_s_barrier();            \
    asm volatile("" ::: "memory");           \
  } while (0)

__device__ __forceinline__ void gload_lds16(const void* g, void* l) {
  __builtin_amdgcn_global_load_lds(
      (const __attribute__((address_space(1))) void*)g,
      (__attribute__((address_space(3))) void*)l, 16, 0, 0);
}

__device__ __forceinline__ float sigmoidf_(float x) {
  return 1.0f / (1.0f + expf(-x));
}

// ---------------------------------------------------------------------------
// Fused prep kernel, range-dispatched on blockIdx.x (unchanged).
//   [0, 8192)     : fp32 -> bf16 weight conversion
//   [8192, 9216)  : beta + xb
//   [9216, 9728)  : RoPE cos/sin table cs[s*64+j]
//   [9728, 9736)  : per-head alpha
// ---------------------------------------------------------------------------
__global__ __launch_bounds__(256) void prep_kernel(
    const float* __restrict__ x, const float* __restrict__ wq,
    const float* __restrict__ wk, const float* __restrict__ wv,
    const float* __restrict__ wo, const float* __restrict__ Wb,
    const float* __restrict__ bbias, const float* __restrict__ alpha_log,
    bf16* __restrict__ wqkvb, bf16* __restrict__ wob, bf16* __restrict__ xb,
    float* __restrict__ beta, float* __restrict__ la_mean,
    float* __restrict__ la_d, float2* __restrict__ cs) {
  const int bid = blockIdx.x;
  const int tid = threadIdx.x;

  if (bid < 8192) {
    size_t i4 = ((size_t)bid * 256 + tid) * 4;
    const float* src;
    bf16* dst;
    size_t off;
    if (i4 < 2097152UL)       { src = wq; dst = wqkvb;           off = i4; }
    else if (i4 < 4194304UL)  { src = wk; dst = wqkvb + 2097152; off = i4 - 2097152UL; }
    else if (i4 < 6291456UL)  { src = wv; dst = wqkvb + 4194304; off = i4 - 4194304UL; }
    else                      { src = wo; dst = wob;             off = i4 - 6291456UL; }
    float4 v = *(const float4*)(src + off);
    bf16x4 o;
    o[0] = (bf16)v.x; o[1] = (bf16)v.y; o[2] = (bf16)v.z; o[3] = (bf16)v.w;
    *(bf16x4*)(dst + off) = o;
  } else if (bid < 9216) {
    const int n = (bid - 8192) * 4 + (tid >> 6);
    const int lane = tid & 63;
    float acc[8];
#pragma unroll
    for (int h = 0; h < 8; h++) acc[h] = 0.0f;
    const float4* x4 = (const float4*)(x + (size_t)n * DMODEL);
    bf16* xbr = xb + (size_t)n * DMODEL;
    for (int d4 = lane; d4 < DMODEL / 4; d4 += 64) {
      float4 xv = x4[d4];
      bf16x4 o;
      o[0] = (bf16)xv.x; o[1] = (bf16)xv.y; o[2] = (bf16)xv.z; o[3] = (bf16)xv.w;
      *(bf16x4*)(xbr + d4 * 4) = o;
#pragma unroll
      for (int h = 0; h < 8; h++) {
        float4 wv2 = ((const float4*)(Wb + (size_t)h * DMODEL))[d4];
        acc[h] += xv.x * wv2.x + xv.y * wv2.y + xv.z * wv2.z + xv.w * wv2.w;
      }
    }
#pragma unroll
    for (int off = 32; off; off >>= 1)
#pragma unroll
      for (int h = 0; h < 8; h++) acc[h] += __shfl_down(acc[h], off);
    if (lane == 0) {
#pragma unroll
      for (int h = 0; h < 8; h++)
        beta[(size_t)n * 8 + h] = sigmoidf_(acc[h] + bbias[h]);
    }
  } else if (bid < 9728) {
    int idx = (bid - 9216) * 256 + tid;  // < 131072 = 2048*64
    int s = idx >> 6, j = idx & 63;
    float f = (float)s * expf(-(float)j * (9.210340371976184f / 64.0f));
    float sn, c;
    sincosf(f, &sn, &c);
    cs[idx] = make_float2(c, sn);
  } else {
    if (tid >= 64) return;
    const int h = bid - 9728;
    const int lane = tid;
    float a1 = sigmoidf_(alpha_log[h * 128 + lane]);
    float a2 = sigmoidf_(alpha_log[h * 128 + 64 + lane]);
    la_d[h * 128 + lane] = logf(a1);
    la_d[h * 128 + 64 + lane] = logf(a2);
    float s = a1 + a2;
    for (int off = 32; off; off >>= 1) s += __shfl_down(s, off);
    if (lane == 0) la_mean[h] = logf(fmaxf(s * (1.0f / 128.0f), 1e-6f));
  }
}

// ---------------------------------------------------------------------------
// QKV projection: 128x384-tile 4-phase bf16 GEMM, full-fill 256 blocks.
// One barrier per phase; counted-vmcnt ledger (unchanged from round 6).
// ---------------------------------------------------------------------------
#define QKV_K 2048
#define QKV_NT 32  // K / 64

__global__ __launch_bounds__(512, 2) void qkv_gemm8p_kernel(
    const bf16* __restrict__ A, const bf16* __restrict__ Bm,
    bf16* __restrict__ C, bf16* __restrict__ vt) {
  __shared__ __align__(16) bf16 smem[2][32768];  // buf: A[0,8192) B[8192,32768)

  const int id = blockIdx.x;
  const int wg = (id & 7) * 32 + (id >> 3);
  const int tile_n = (wg >> 5) * 384;
  const int tile_m = (wg & 31) * 128;

  const int tid = threadIdx.x;
  const int lane = tid & 63;
  const int w = tid >> 6;
  const int wm = w >> 2;  // 0..1 -> rows wm*64
  const int wn = w & 3;   // 0..3 -> cols wn*96
  const int lr = lane & 15;
  const int kq = lane >> 4;

  const int srow = lane >> 3;
  const int slot = lane & 7;
  const int sgo = (slot ^ srow) * 8;
  const int rloc = w * 8 + srow;

  size_t Aoff[2], Boff[6];
#pragma unroll
  for (int a = 0; a < 2; ++a)
    Aoff[a] = (size_t)(tile_m + a * 64 + rloc) * QKV_K + sgo;
#pragma unroll
  for (int b = 0; b < 6; ++b) {
    const int ldsr = b * 64 + rloc;
    const int qn = ldsr >= 192 ? 1 : 0;
    const int rem = ldsr - qn * 192;
    const int wng = rem / 48;
    const int rr = rem - wng * 48;
    const int gcol = wng * 96 + qn * 48 + rr;
    Boff[b] = (size_t)(tile_n + gcol) * QKV_K + sgo;
  }

  f32x4 acc[4][6];
#pragma unroll
  for (int i = 0; i < 4; i++)
#pragma unroll
    for (int j = 0; j < 6; j++) acc[i][j] = (f32x4){0.f, 0.f, 0.f, 0.f};

  auto stageAA = [&](int buf, int k0) {
#pragma unroll
    for (int a = 0; a < 2; ++a)
      gload_lds16(A + Aoff[a] + k0, &smem[buf][(a * 64 + w * 8) * 64]);
  };
  auto stageB2 = [&](int buf, int k0, int b0) {
#pragma unroll
    for (int u = 0; u < 2; ++u)
      gload_lds16(Bm + Boff[b0 + u] + k0,
                  &smem[buf][8192 + ((b0 + u) * 64 + w * 8) * 64]);
  };

  // prologue (order matters for the ledger)
  stageAA(0, 0);
  stageB2(0, 0, 0);
  stageB2(0, 0, 2);
  stageAA(1, 64);
  stageB2(0, 0, 4);
  VMCNT(4);
  BAR();

  for (int t = 0; t < QKV_NT; ++t) {
    const int buf = t & 1;
    const int k0n = (t + 1) * 64;
    const bool h1 = (t + 1 < QKV_NT);
    const bool h2 = (t + 2 < QKV_NT);
    const bf16* ldsA = smem[buf];
    const bf16* ldsB = smem[buf] + 8192;

    bf16x8 af[2][2], b0f[3][2], b1f[3][2];

    // ---- p0: read A-q0 + B-q0; stage b01(t+1); MFMA (0,0..2) ----
#pragma unroll
    for (int mi = 0; mi < 2; ++mi)
#pragma unroll
      for (int ks = 0; ks < 2; ++ks)
        af[mi][ks] = *(const bf16x8*)&ldsA[(wm * 64 + mi * 16 + lr) * 64 +
                                           (((ks * 4 + kq) ^ (lr & 7)) * 8)];
#pragma unroll
    for (int ni = 0; ni < 3; ++ni)
#pragma unroll
      for (int ks = 0; ks < 2; ++ks)
        b0f[ni][ks] = *(const bf16x8*)&ldsB[(wn * 48 + ni * 16 + lr) * 64 +
                                            (((ks * 4 + kq) ^ (lr & 7)) * 8)];
    if (h1) stageB2(buf ^ 1, k0n, 0);
    __builtin_amdgcn_s_setprio(1);
#pragma unroll
    for (int mi = 0; mi < 2; ++mi)
#pragma unroll
      for (int ni = 0; ni < 3; ++ni)
#pragma unroll
        for (int ks = 0; ks < 2; ++ks)
          acc[mi][ni] = __builtin_amdgcn_mfma_f32_16x16x32_bf16(
              af[mi][ks], b0f[ni][ks], acc[mi][ni], 0, 0, 0);
    __builtin_amdgcn_s_setprio(0);
    if (h1) VMCNT(4);
    else VMCNT(0);
    BAR();

    // ---- p1: read B-q1; stage b23(t+1); MFMA (0,3..5) ----
#pragma unroll
    for (int ni = 0; ni < 3; ++ni)
#pragma unroll
      for (int ks = 0; ks < 2; ++ks)
        b1f[ni][ks] = *(const bf16x8*)&ldsB[(192 + wn * 48 + ni * 16 + lr) * 64 +
                                            (((ks * 4 + kq) ^ (lr & 7)) * 8)];
    if (h1) stageB2(buf ^ 1, k0n, 2);
    __builtin_amdgcn_s_setprio(1);
#pragma unroll
    for (int mi = 0; mi < 2; ++mi)
#pragma unroll
      for (int ni = 0; ni < 3; ++ni)
#pragma unroll
        for (int ks = 0; ks < 2; ++ks)
          acc[mi][3 + ni] = __builtin_amdgcn_mfma_f32_16x16x32_bf16(
              af[mi][ks], b1f[ni][ks], acc[mi][3 + ni], 0, 0, 0);
    __builtin_amdgcn_s_setprio(0);
    BAR();

    // ---- p2: read A-q1 (overwrite); stage b45(t+1); MFMA (1,3..5) ----
#pragma unroll
    for (int mi = 0; mi < 2; ++mi)
#pragma unroll
      for (int ks = 0; ks < 2; ++ks)
        af[mi][ks] = *(const bf16x8*)&ldsA[(wm * 64 + 32 + mi * 16 + lr) * 64 +
                                           (((ks * 4 + kq) ^ (lr & 7)) * 8)];
    if (h1) stageB2(buf ^ 1, k0n, 4);
    __builtin_amdgcn_s_setprio(1);
#pragma unroll
    for (int mi = 0; mi < 2; ++mi)
#pragma unroll
      for (int ni = 0; ni < 3; ++ni)
#pragma unroll
        for (int ks = 0; ks < 2; ++ks)
          acc[2 + mi][3 + ni] = __builtin_amdgcn_mfma_f32_16x16x32_bf16(
              af[mi][ks], b1f[ni][ks], acc[2 + mi][3 + ni], 0, 0, 0);
    __builtin_amdgcn_s_setprio(0);
    BAR();

    // ---- p3: stage A(t+2) into CURRENT buf; MFMA (1,0..2) ----
    if (h2) stageAA(buf, (t + 2) * 64);
    __builtin_amdgcn_s_setprio(1);
#pragma unroll
    for (int mi = 0; mi < 2; ++mi)
#pragma unroll
      for (int ni = 0; ni < 3; ++ni)
#pragma unroll
        for (int ks = 0; ks < 2; ++ks)
          acc[2 + mi][ni] = __builtin_amdgcn_mfma_f32_16x16x32_bf16(
              af[mi][ks], b0f[ni][ks], acc[2 + mi][ni], 0, 0, 0);
    __builtin_amdgcn_s_setprio(0);
    if (h1) {
      if (h2) VMCNT(4);
      else VMCNT(2);
    }
    BAR();
  }

  const int rb = kq * 4;
#pragma unroll
  for (int mi = 0; mi < 4; ++mi) {
    const int row0 = tile_m + wm * 64 + mi * 16 + rb;
#pragma unroll
    for (int ni = 0; ni < 6; ++ni) {
      const int col = tile_n + wn * 96 + ni * 16 + lr;
      const int z = col >> 10;
      const int cz = col & 1023;
      bf16* Cz = C + (size_t)z * 4194304UL;
#pragma unroll
      for (int r2 = 0; r2 < 4; ++r2)
        Cz[(size_t)(row0 + r2) * 1024 + cz] = (bf16)acc[mi][ni][r2];
      if (z == 2) {
        const int bb2 = row0 >> 11;
        const int ss = row0 & 2047;
        bf16x4 o4;
#pragma unroll
        for (int r2 = 0; r2 < 4; ++r2) o4[r2] = (bf16)acc[mi][ni][r2];
        *(bf16x4*)&vt[(((size_t)bb2 * 8 + (cz >> 7)) * 128 + (cz & 127)) * 2048 +
                      ss] = o4;
      }
    }
  }
}

// ---------------------------------------------------------------------------
// Output projection (bid<256) + state reduce (bid>=256), fused launch.
// GEMM core unchanged from round 6.
// ---------------------------------------------------------------------------
#define OP_K 1024
#define OP_NT 16  // K / 64

__global__ __launch_bounds__(512, 2) void oproj_kernel(
    const bf16* __restrict__ A, const bf16* __restrict__ Bm,
    float* __restrict__ C, const float* __restrict__ part) {
  __shared__ __align__(16) bf16 smem[2][24576];  // A[0,8192) B[8192,24576)

  const int id = blockIdx.x;
  const int tid = threadIdx.x;

  if (id >= 256) {
    // ---- state reduce: sum 16 chunk partials ----
    size_t off = (((size_t)id - 256) * 512 + tid) * 4;
    float4 s = {0.f, 0.f, 0.f, 0.f};
#pragma unroll
    for (int c = 0; c < 16; c++) {
      float4 p = *(const float4*)&part[(size_t)c * 262144 + off];
      s.x += p.x; s.y += p.y; s.z += p.z; s.w += p.w;
    }
    *(float4*)&(C + 8388608UL)[off] = s;
    return;
  }

  const int wg = (id & 7) * 32 + (id >> 3);
  const int tile_n = (wg >> 5) * 256;
  const int tile_m = (wg & 31) * 128;

  const int lane = tid & 63;
  const int w = tid >> 6;
  const int wm = w >> 2;  // 0..1
  const int wn = w & 3;   // 0..3
  const int lr = lane & 15;
  const int kq = lane >> 4;

  const int srow = lane >> 3;
  const int slot = lane & 7;
  const int sgo = (slot ^ srow) * 8;
  const int rloc = w * 8 + srow;

  size_t Aoff[2], Boff[4];
#pragma unroll
  for (int a = 0; a < 2; ++a)
    Aoff[a] = (size_t)(tile_m + a * 64 + rloc) * OP_K + sgo;
#pragma unroll
  for (int b = 0; b < 4; ++b) {
    const int ldsr = b * 64 + rloc;
    const int qn = ldsr >= 128 ? 1 : 0;
    const int rem = ldsr - qn * 128;
    const int wng = rem >> 5;
    const int rr = rem & 31;
    const int gcol = wng * 64 + qn * 32 + rr;
    Boff[b] = (size_t)(tile_n + gcol) * OP_K + sgo;
  }

  f32x4 acc[4][4];
#pragma unroll
  for (int i = 0; i < 4; i++)
#pragma unroll
    for (int j = 0; j < 4; j++) acc[i][j] = (f32x4){0.f, 0.f, 0.f, 0.f};

  auto stageAA = [&](int buf, int k0) {
#pragma unroll
    for (int a = 0; a < 2; ++a)
      gload_lds16(A + Aoff[a] + k0, &smem[buf][(a * 64 + w * 8) * 64]);
  };
  auto stageB2 = [&](int buf, int k0, int b0) {
#pragma unroll
    for (int u = 0; u < 2; ++u)
      gload_lds16(Bm + Boff[b0 + u] + k0,
                  &smem[buf][8192 + ((b0 + u) * 64 + w * 8) * 64]);
  };

  // prologue
  stageAA(0, 0);
  stageB2(0, 0, 0);
  stageAA(1, 64);
  stageB2(0, 0, 2);
  VMCNT(4);
  BAR();

  for (int t = 0; t < OP_NT; ++t) {
    const int buf = t & 1;
    const int k0n = (t + 1) * 64;
    const bool h1 = (t + 1 < OP_NT);
    const bool h2 = (t + 2 < OP_NT);
    const bf16* ldsA = smem[buf];
    const bf16* ldsB = smem[buf] + 8192;

    bf16x8 af[2][2], b0f[2][2], b1f[2][2];

    // ---- p0 ----
#pragma unroll
    for (int mi = 0; mi < 2; ++mi)
#pragma unroll
      for (int ks = 0; ks < 2; ++ks)
        af[mi][ks] = *(const bf16x8*)&ldsA[(wm * 64 + mi * 16 + lr) * 64 +
                                           (((ks * 4 + kq) ^ (lr & 7)) * 8)];
#pragma unroll
    for (int ni = 0; ni < 2; ++ni)
#pragma unroll
      for (int ks = 0; ks < 2; ++ks)
        b0f[ni][ks] = *(const bf16x8*)&ldsB[(wn * 32 + ni * 16 + lr) * 64 +
                                            (((ks * 4 + kq) ^ (lr & 7)) * 8)];
    if (h1) stageB2(buf ^ 1, k0n, 0);
    __builtin_amdgcn_s_setprio(1);
#pragma unroll
    for (int mi = 0; mi < 2; ++mi)
#pragma unroll
      for (int ni = 0; ni < 2; ++ni)
#pragma unroll
        for (int ks = 0; ks < 2; ++ks)
          acc[mi][ni] = __builtin_amdgcn_mfma_f32_16x16x32_bf16(
              af[mi][ks], b0f[ni][ks], acc[mi][ni], 0, 0, 0);
    __builtin_amdgcn_s_setprio(0);
    if (h1) VMCNT(4);
    else VMCNT(0);
    BAR();

    // ---- p1 ----
#pragma unroll
    for (int ni = 0; ni < 2; ++ni)
#pragma unroll
      for (int ks = 0; ks < 2; ++ks)
        b1f[ni][ks] = *(const bf16x8*)&ldsB[(128 + wn * 32 + ni * 16 + lr) * 64 +
                                            (((ks * 4 + kq) ^ (lr & 7)) * 8)];
    if (h1) stageB2(buf ^ 1, k0n, 2);
    __builtin_amdgcn_s_setprio(1);
#pragma unroll
    for (int mi = 0; mi < 2; ++mi)
#pragma unroll
      for (int ni = 0; ni < 2; ++ni)
#pragma unroll
        for (int ks = 0; ks < 2; ++ks)
          acc[mi][2 + ni] = __builtin_amdgcn_mfma_f32_16x16x32_bf16(
              af[mi][ks], b1f[ni][ks], acc[mi][2 + ni], 0, 0, 0);
    __builtin_amdgcn_s_setprio(0);
    BAR();

    // ---- p2 ----
#pragma unroll
    for (int mi = 0; mi < 2; ++mi)
#pragma unroll
      for (int ks = 0; ks < 2; ++ks)
        af[mi][ks] = *(const bf16x8*)&ldsA[(wm * 64 + 32 + mi * 16 + lr) * 64 +
                                           (((ks * 4 + kq) ^ (lr & 7)) * 8)];
    __builtin_amdgcn_s_setprio(1);
#pragma unroll
    for (int mi = 0; mi < 2; ++mi)
#pragma unroll
      for (int ni = 0; ni < 2; ++ni)
#pragma unroll
        for (int ks = 0; ks < 2; ++ks)
          acc[2 + mi][2 + ni] = __builtin_amdgcn_mfma_f32_16x16x32_bf16(
              af[mi][ks], b1f[ni][ks], acc[2 + mi][2 + ni], 0, 0, 0);
    __builtin_amdgcn_s_setprio(0);
    BAR();

    // ---- p3 ----
    if (h2) stageAA(buf, (t + 2) * 64);
    __builtin_amdgcn_s_setprio(1);
#pragma unroll
    for (int mi = 0; mi < 2; ++mi)
#pragma unroll
      for (int ni = 0; ni < 2; ++ni)
#pragma unroll
        for (int ks = 0; ks < 2; ++ks)
          acc[2 + mi][ni] = __builtin_amdgcn_mfma_f32_16x16x32_bf16(
              af[mi][ks], b0f[ni][ks], acc[2 + mi][ni], 0, 0, 0);
    __builtin_amdgcn_s_setprio(0);
    if (h1) {
      if (h2) VMCNT(4);
      else VMCNT(2);
    }
    BAR();
  }

  // epilogue: fp32 C
  const int rb = kq * 4;
#pragma unroll
  for (int i = 0; i < 4; ++i) {
    const int row0 = tile_m + wm * 64 + (i >> 1) * 32 + (i & 1) * 16 + rb;
#pragma unroll
    for (int j = 0; j < 4; ++j) {
      const int col = tile_n + wn * 64 + (j >> 1) * 32 + (j & 1) * 16 + lr;
#pragma unroll
      for (int r2 = 0; r2 < 4; ++r2)
        C[(size_t)(row0 + r2) * 2048 + col] = acc[i][j][r2];
    }
  }
}

// ---------------------------------------------------------------------------
// MFMA banded-decay attention with FUSED RoPE (q and k rotated in-register
// from the cs table; bf16-rounded to match the old rope-kernel numerics).
// Fragment pair (ks, ks+2) holds (d, d+64) for the same row — rotation is
// lane-local. k rows clamped to 0 rope with cs[0..]=(1,0) => identity.
// ---------------------------------------------------------------------------
__global__ __launch_bounds__(256) void attn_mfma_kernel(
    const bf16* __restrict__ q, const bf16* __restrict__ k,
    const bf16* __restrict__ vt, const float* __restrict__ beta,
    const float* __restrict__ la_mean, const float2* __restrict__ cs,
    bf16* __restrict__ outb) {
  const int s0 = blockIdx.x * 64;
  const int h = blockIdx.y;
  const int b = blockIdx.z;
  const int tid = threadIdx.x;
  const int w = tid >> 6;
  const int lane = tid & 63;
  const int lr = lane & 15;
  const int kq = lane >> 4;  // quad
  const float la = la_mean[h];

  __shared__ __align__(16) bf16 Ps[4][2][16][72];

  const int sg = s0 + w * 16;
  const size_t qbase =
      ((size_t)b * S_LEN + (sg + lr)) * INNER_DIM + h * 128 + kq * 8;
  bf16x8 aq[4];
#pragma unroll
  for (int ks = 0; ks < 4; ks++)
    aq[ks] = *(const bf16x8*)&q[qbase + ks * 32];
  // rope q
  {
    const float2* cq = cs + (size_t)(sg + lr) * 64 + kq * 8;
#pragma unroll
    for (int ks2 = 0; ks2 < 2; ++ks2)
#pragma unroll
      for (int j = 0; j < 8; ++j) {
        float2 cv = cq[ks2 * 32 + j];
        float lo = (float)aq[ks2][j], hi = (float)aq[ks2 + 2][j];
        aq[ks2][j] = (bf16)(lo * cv.x - hi * cv.y);
        aq[ks2 + 2][j] = (bf16)(hi * cv.x + lo * cv.y);
      }
  }

  f32x4 O[8];
#pragma unroll
  for (int en = 0; en < 8; en++) O[en] = (f32x4){0.f, 0.f, 0.f, 0.f};

  const size_t kbase = (size_t)b * S_LEN * INNER_DIM + h * 128 + kq * 8;
  const size_t vtbase = ((size_t)b * 8 + h) * 128 * 2048;

#pragma unroll
  for (int tile = 0; tile < 2; tile++) {
    const int tb = s0 - 64 + tile * 64;
    f32x4 sc[4];
#pragma unroll
    for (int nt = 0; nt < 4; nt++) sc[nt] = (f32x4){0.f, 0.f, 0.f, 0.f};
#pragma unroll
    for (int nt = 0; nt < 4; nt++) {
      int t = tb + nt * 16 + lr;
      int tc = t > 0 ? t : 0;
      const bf16* krow = &k[kbase + (size_t)tc * INNER_DIM];
      bf16x8 bk4[4];
#pragma unroll
      for (int ks = 0; ks < 4; ks++)
        bk4[ks] = *(const bf16x8*)&krow[ks * 32];
      // rope k row
      const float2* ck = cs + (size_t)tc * 64 + kq * 8;
#pragma unroll
      for (int ks2 = 0; ks2 < 2; ++ks2)
#pragma unroll
        for (int j = 0; j < 8; ++j) {
          float2 cv = ck[ks2 * 32 + j];
          float lo = (float)bk4[ks2][j], hi = (float)bk4[ks2 + 2][j];
          bk4[ks2][j] = (bf16)(lo * cv.x - hi * cv.y);
          bk4[ks2 + 2][j] = (bf16)(hi * cv.x + lo * cv.y);
        }
#pragma unroll
      for (int ks = 0; ks < 4; ks++)
        sc[nt] = __builtin_amdgcn_mfma_f32_16x16x32_bf16(aq[ks], bk4[ks],
                                                         sc[nt], 0, 0, 0);
    }
#pragma unroll
    for (int nt = 0; nt < 4; nt++) {
      int t = tb + nt * 16 + lr;
      int tc = t > 0 ? t : 0;
      float bt = beta[((size_t)b * S_LEN + tc) * 8 + h];
#pragma unroll
      for (int reg = 0; reg < 4; reg++) {
        int qrow = sg + kq * 4 + reg;
        int td = qrow - t;
        float wgt = 0.0f;
        if (t >= 0 && td >= 0 && td < 64)
          wgt = sc[nt][reg] * __expf((float)td * la) * bt;
        Ps[w][tile][kq * 4 + reg][nt * 16 + lr] = (bf16)wgt;
      }
    }
    __syncthreads();
    bf16x8 ap[2];
#pragma unroll
    for (int ks2 = 0; ks2 < 2; ks2++)
      ap[ks2] = *(const bf16x8*)&Ps[w][tile][lr][ks2 * 32 + kq * 8];
#pragma unroll
    for (int en = 0; en < 8; en++) {
#pragma unroll
      for (int ks2 = 0; ks2 < 2; ks2++) {
        int t0f = tb + ks2 * 32 + kq * 8;
        int tcf = t0f > 0 ? t0f : 0;
        bf16x8 bv = *(const bf16x8*)&vt[vtbase + (size_t)(en * 16 + lr) * 2048 +
                                        tcf];
        O[en] = __builtin_amdgcn_mfma_f32_16x16x32_bf16(ap[ks2], bv, O[en], 0,
                                                        0, 0);
      }
    }
  }
  const size_t obase = (size_t)b * S_LEN * INNER_DIM + h * 128;
#pragma unroll
  for (int en = 0; en < 8; en++) {
#pragma unroll
    for (int reg = 0; reg < 4; reg++) {
      int qrow = sg + kq * 4 + reg;
      outb[obase + (size_t)qrow * INNER_DIM + en * 16 + lr] =
          (bf16)O[en][reg];
    }
  }
}

// ---------------------------------------------------------------------------
// Stage 1: partial state per 32-step chunk. RoPE fused into k staging
// (bf16-rounded, identical numerics to old rope-then-read path).
// ---------------------------------------------------------------------------
__global__ __launch_bounds__(256) void state_partial_kernel(
    const bf16* __restrict__ k, const bf16* __restrict__ v,
    const float* __restrict__ beta, const float* __restrict__ la_d,
    const float2* __restrict__ cs, float* __restrict__ part) {
  const int bh = blockIdx.x;
  const int chunk = blockIdx.y;
  const int b = bh >> 3, h = bh & 7;
  const int t0 = S_LEN - 512 + chunk * 32;
  const int tid = threadIdx.x;
  const int d = tid >> 1;
  const int eh = (tid & 1) * 64;

  __shared__ float ks[32][128];
  __shared__ float vsm[32][128];
  __shared__ float bs[32];

  const size_t bh_off = ((size_t)b * S_LEN) * INNER_DIM + (size_t)h * 128;
  // k staging with rope: 256 pairs (32 rows x 8 low-chunks), 1 per thread
  {
    int r = tid >> 3, c8l = (tid & 7) * 8;  // c8l in 0..56
    const bf16* kr = &k[bh_off + (size_t)(t0 + r) * INNER_DIM];
    bf16x8 klo = *(const bf16x8*)&kr[c8l];
    bf16x8 khi = *(const bf16x8*)&kr[c8l + 64];
    const float2* cr = cs + (size_t)(t0 + r) * 64 + c8l;
#pragma unroll
    for (int j = 0; j < 8; j++) {
      float2 cv = cr[j];
      float lo = (float)klo[j], hi = (float)khi[j];
      ks[r][c8l + j] = (float)(bf16)(lo * cv.x - hi * cv.y);
      ks[r][c8l + 64 + j] = (float)(bf16)(hi * cv.x + lo * cv.y);
    }
  }
  // v staging (unroped)
  for (int u = tid; u < 32 * 16; u += 256) {
    int r = u >> 4, c8 = (u & 15) * 8;
    bf16x8 vv8 = *(const bf16x8*)&v[bh_off + (size_t)(t0 + r) * INNER_DIM + c8];
#pragma unroll
    for (int j = 0; j < 8; j++) vsm[r][c8 + j] = (float)vv8[j];
  }
  if (tid < 32) bs[tid] = beta[((size_t)b * S_LEN + t0 + tid) * 8 + h];
  __syncthreads();

  const float lad = la_d[h * 128 + d];
  float acc[64];
#pragma unroll
  for (int e = 0; e < 64; e++) acc[e] = 0.0f;

  for (int tl = 0; tl < 32; tl++) {
    int m = (S_LEN - 1) - (t0 + tl);
    float f = __expf((float)m * lad);
    float coef = bs[tl] * ks[tl][d] * f;
    if (coef != 0.0f) {
#pragma unroll
      for (int e = 0; e < 64; e += 4) {
        float4 vv4 = *(const float4*)&vsm[tl][eh + e];
        acc[e + 0] = fmaf(coef, vv4.x, acc[e + 0]);
        acc[e + 1] = fmaf(coef, vv4.y, acc[e + 1]);
        acc[e + 2] = fmaf(coef, vv4.z, acc[e + 2]);
        acc[e + 3] = fmaf(coef, vv4.w, acc[e + 3]);
      }
    }
  }
  float* pp = part + (((size_t)chunk * 16 + bh) * 16384 + (size_t)d * 128 + eh);
#pragma unroll
  for (int e = 0; e < 64; e += 4) {
    float4 o = {acc[e + 0], acc[e + 1], acc[e + 2], acc[e + 3]};
    *(float4*)&pp[e] = o;
  }
}

// ---------------------------------------------------------------------------
extern "C" void kernel_launch(void* const* d_in, const int* in_sizes, int n_in,
                              void* d_out, int out_size, void* d_ws,
                              size_t ws_size, hipStream_t stream) {
  const float* x = (const float*)d_in[0];
  const float* Wq = (const float*)d_in[1];
  const float* Wk = (const float*)d_in[2];
  const float* Wv = (const float*)d_in[3];
  const float* Wo = (const float*)d_in[4];
  const float* Wb = (const float*)d_in[5];
  const float* bb = (const float*)d_in[6];
  const float* alog = (const float*)d_in[7];
  float* out = (float*)d_out;

  char* ws = (char*)d_ws;
  bf16* xb = (bf16*)(ws);                      // 16 MB
  float* part = (float*)(ws);                  // reuses xb after QKV GEMM
  bf16* wqkvb = (bf16*)(ws + 16777216UL);      // 12 MB
  bf16* wob = (bf16*)(ws + 29360128UL);        // 4 MB
  bf16* q = (bf16*)(ws + 33554432UL);          // 8 MB
  bf16* kk = (bf16*)(ws + 41943040UL);         // 8 MB
  bf16* vv = (bf16*)(ws + 50331648UL);         // 8 MB
  bf16* attnb = (bf16*)(ws + 58720256UL);      // 8 MB
  bf16* vt = (bf16*)(ws + 67108864UL);         // 8 MB (V transposed)
  float* beta = (float*)(ws + 75497472UL);     // 128 KB
  float* la_mean = (float*)(ws + 75628544UL);  // 32 B
  float* la_d = (float*)(ws + 75628800UL);     // 4 KB
  float2* cs = (float2*)(ws + 75632896UL);     // 1 MB rope table

  prep_kernel<<<9736, 256, 0, stream>>>(x, Wq, Wk, Wv, Wo, Wb, bb, alog,
                                        wqkvb, wob, xb, beta, la_mean, la_d,
                                        cs);
  qkv_gemm8p_kernel<<<256, 512, 0, stream>>>(xb, wqkvb, q, vt);
  attn_mfma_kernel<<<dim3(S_LEN / 64, NHEADS, BATCH), 256, 0, stream>>>(
      q, kk, vt, beta, la_mean, cs, attnb);
  state_partial_kernel<<<dim3(16, 16), 256, 0, stream>>>(kk, vv, beta, la_d,
                                                         cs, part);
  // output projection (256 blocks) + state reduce (128 blocks), fused
  oproj_kernel<<<384, 512, 0, stream>>>(attnb, wob, out, part);
}